// Round 7
// baseline (119.897 us; speedup 1.0000x reference)
//
#include <hip/hip_runtime.h>
#include <hip/hip_bf16.h>

// ---------------------------------------------------------------------------
// KroneNet fused kernel v7 for MI355X (gfx950)
// out[i][j] = softmax_j( s_a[i] * t_j[i] )
// History: v4 46.5us (dual-path, 0 spill, fences). v5 151us (reg cap < acc
// footprint -> spill; VGPR+AGPR unified!). v6 119us total: split kernels,
// ~23us each -- but two dependent dispatches + s_a global roundtrip ate the
// gain. Harness floor identified: 268MB d_ws poison fill (~40us) + ~34us
// restore/graph overhead is inside dur_us every round.
// v7: ONE kernel, sequential path phases per block; W2b re-packed over W2a
// mid-kernel; s_a lives in LDS; all x loads issued at kernel top (fences no
// longer delay them). Fences retained at phase boundaries (spill killer).
// ---------------------------------------------------------------------------

#define BTOT 262144
#define NBLK (BTOT / 256)   // 1024 blocks x 256 samples (2 chunks of 128)

typedef __attribute__((ext_vector_type(4))) float floatx4;
typedef __attribute__((ext_vector_type(8))) short bf16x8;
typedef __attribute__((ext_vector_type(4))) int  intx4;

// LDS layout (bytes), one path resident at a time
#define OFF_W2  0          // 4 ksteps * 8 ntiles * 64 lanes * 16B = 32768
#define OFF_W1  32768      // 144 * float4 (128 + 16 pad slots)    = 2304
#define OFF_B2  35072      // 128 * float                          = 512
#define OFF_W3  35584      // 384 * float (a uses 128, b uses 384) = 1536
#define OFF_SA  37120      // 256 * float (s_a per sample)         = 1024
#define LDS_TOTAL 38144

// pack two fp32 -> one dword of two bf16 (round-half-up), 3 VALU ops
static __device__ __forceinline__ int pack2bf(float lo, float hi) {
    unsigned a = __builtin_bit_cast(unsigned, lo) + 0x8000u;
    unsigned b = __builtin_bit_cast(unsigned, hi) + 0x8000u;
    return (int)__builtin_amdgcn_perm(b, a, 0x07060302u); // {b.hi16, a.hi16}
}

// compile-time-indexed 4-way select (NO dynamic register indexing)
#define SEL4(a0, a1, a2, a3, i) \
    ((i) == 0 ? (a0) : (i) == 1 ? (a1) : (i) == 2 ? (a2) : (a3))

static __device__ __forceinline__ float redcol(float v) {
    v += __shfl_xor(v, 1); v += __shfl_xor(v, 2);
    v += __shfl_xor(v, 4); v += __shfl_xor(v, 8);
    return v;
}

// W1 slot with bank-conflict padding: one extra float4 slot every 8 entries
static __device__ __forceinline__ int w1slot(int k) { return k + (k >> 3); }

// Pack one path's W2/W1/b1/b2 into LDS.
// W2 mapping (verified v5/v6): float4 group u = n*32+k4, k = 4*k4:
// dest = (s*8+t)*1024 + l*16 + (k&7)*2, s=k>>5, l=((k&31)>>3)*16+(n&15),
// t = n>>4.  B-frag: lane holds B[k=quad*8+j][n=col].
static __device__ __forceinline__ void pack_path(
        unsigned char* smem, int tid,
        const float* __restrict__ w2, const float* __restrict__ w1,
        const float* __restrict__ b1, const float* __restrict__ b2) {
    const float4* w2p = (const float4*)w2;
    #pragma unroll
    for (int i = 0; i < 16; ++i) {
        int u = i * 256 + tid;        // u = n*32 + k4
        int n = u >> 5;
        float4 f = w2p[u];
        int k = (u & 31) * 4;
        int s = k >> 5;
        int j0 = k & 7;               // 0 or 4
        int l = ((k & 31) >> 3) * 16 + (n & 15);
        int2 pkd;
        pkd.x = pack2bf(f.x, f.y);
        pkd.y = pack2bf(f.z, f.w);
        *(int2*)(smem + OFF_W2 + (s * 8 + (n >> 4)) * 1024 + l * 16 + j0 * 2) = pkd;
    }
    if (tid < 128) {
        ((float4*)(smem + OFF_W1))[w1slot(tid)] =
            make_float4(w1[2 * tid], w1[2 * tid + 1], b1[tid], 0.f);
        ((float*)(smem + OFF_B2))[tid] = b2[tid];
    }
}

// One chunk's GEMM: acc = W2 . relu(W1.x+b1) + b2 (acc pre-init with b2).
// acc layout: (t, mt, r) -> sample mt*16+quad*4+r, n = t*16+col.
#define GEMM_CHUNK(acc, XV, W1p, W2p, B2p)                                     \
    {                                                                          \
        _Pragma("unroll")                                                      \
        for (int t = 0; t < 8; ++t) {                                          \
            float b2n = (B2p)[t * 16 + col];                                   \
            floatx4 bi = (floatx4){b2n, b2n, b2n, b2n};                        \
            _Pragma("unroll")                                                  \
            for (int mt = 0; mt < 2; ++mt) acc[t][mt] = bi;                    \
        }                                                                      \
        _Pragma("unroll")                                                      \
        for (int s = 0; s < 4; ++s) {                                          \
            intx4 af[2];                                                       \
            const int bslot = s * 36 + quad * 9;                               \
            _Pragma("unroll")                                                  \
            for (int j2 = 0; j2 < 4; ++j2) {                                   \
                float4 c0 = (W1p)[bslot + 2 * j2];                             \
                float4 c1 = (W1p)[bslot + 2 * j2 + 1];                         \
                _Pragma("unroll")                                              \
                for (int mt = 0; mt < 2; ++mt) {                               \
                    float h0 = fmaxf(fmaf((XV)[mt].x, c0.x,                    \
                                fmaf((XV)[mt].y, c0.y, c0.z)), 0.f);           \
                    float h1 = fmaxf(fmaf((XV)[mt].x, c1.x,                    \
                                fmaf((XV)[mt].y, c1.y, c1.z)), 0.f);           \
                    af[mt][j2] = pack2bf(h0, h1);                              \
                }                                                              \
            }                                                                  \
            _Pragma("unroll")                                                  \
            for (int t = 0; t < 8; ++t) {                                      \
                bf16x8 bfr = (W2p)[(s * 8 + t) * 64 + lane];                   \
                _Pragma("unroll")                                              \
                for (int mt = 0; mt < 2; ++mt)                                 \
                    acc[t][mt] = __builtin_amdgcn_mfma_f32_16x16x32_bf16(      \
                        __builtin_bit_cast(bf16x8, af[mt]), bfr,               \
                        acc[t][mt], 0, 0, 0);                                  \
            }                                                                  \
        }                                                                      \
    }

// ---------------------------------------------------------------------------
// 1024 blocks x 256 threads (4 waves). Per block (256 samples):
//   preload x (both paths, both chunks) -> pack a -> phase a (s_a -> LDS)
//   -> repack b -> phase b (t_j, softmax with LDS s_a, store out)
// ---------------------------------------------------------------------------
__global__ __launch_bounds__(256, 2)
void krone_fused(const float* __restrict__ x,
                 const float* __restrict__ w1a, const float* __restrict__ w1b,
                 const float* __restrict__ b1a, const float* __restrict__ b1b,
                 const float* __restrict__ w2a, const float* __restrict__ w2b,
                 const float* __restrict__ b2a, const float* __restrict__ b2b,
                 const float* __restrict__ w3a, const float* __restrict__ w3b,
                 const float* __restrict__ b3a, const float* __restrict__ b3b,
                 float* __restrict__ out) {
    __shared__ __align__(16) unsigned char smem[LDS_TOTAL];

    const int tid  = threadIdx.x;
    const int lane = tid & 63;
    const int wave = tid >> 6;
    const int quad = lane >> 4;
    const int col  = lane & 15;

    // ---- preload all x up front (fences below can no longer delay these) ----
    const float2* xA = (const float2*)x;
    const float2* xB = xA + BTOT;
    float2 xa[4], xb[4];   // [c*2 + mt]
    #pragma unroll
    for (int c = 0; c < 2; ++c)
        #pragma unroll
        for (int mt = 0; mt < 2; ++mt) {
            int idx = blockIdx.x * 256 + c * 128 + wave * 32 + mt * 16 + col;
            xa[c * 2 + mt] = xA[idx];
            xb[c * 2 + mt] = xB[idx];
        }
    const float b3a_ = b3a[0];
    const float b30 = b3b[0], b31 = b3b[1], b32 = b3b[2];

    const bf16x8* W2 = (const bf16x8*)(smem + OFF_W2);
    const float4* W1 = (const float4*)(smem + OFF_W1);
    const float*  B2 = (const float*)(smem + OFF_B2);
    const float*  W3 = (const float*)(smem + OFF_W3);
    float*        SA = (float*)(smem + OFF_SA);

    // ---- phase a: pack + compute s_a into LDS ----
    pack_path(smem, tid, w2a, w1a, b1a, b2a);
    if (tid < 128) ((float*)(smem + OFF_W3))[tid] = w3a[tid];
    __syncthreads();

    #pragma unroll
    for (int c = 0; c < 2; ++c) {
        __builtin_amdgcn_sched_barrier(0);
        floatx4 acc[8][2];
        GEMM_CHUNK(acc, xa + 2 * c, W1, W2, B2);
        __builtin_amdgcn_sched_barrier(0);

        float pa[2][4] = {};
        #pragma unroll
        for (int t = 0; t < 8; ++t) {
            float w3n = W3[t * 16 + col];
            #pragma unroll
            for (int mt = 0; mt < 2; ++mt)
                #pragma unroll
                for (int r = 0; r < 4; ++r)
                    pa[mt][r] = fmaf(w3n, fmaxf(acc[t][mt][r], 0.f), pa[mt][r]);
        }
        #pragma unroll
        for (int mt = 0; mt < 2; ++mt)
            #pragma unroll
            for (int r = 0; r < 4; ++r) pa[mt][r] = redcol(pa[mt][r]);
        __builtin_amdgcn_sched_barrier(0);

        if (col < 4) {
            #pragma unroll
            for (int mt = 0; mt < 2; ++mt) {
                int sl = mt * 16 + quad * 4 + col;
                SA[c * 128 + wave * 32 + sl] =
                    SEL4(pa[mt][0], pa[mt][1], pa[mt][2], pa[mt][3], col) + b3a_;
            }
        }
        __builtin_amdgcn_sched_barrier(0);
    }

    // ---- repack for path b ----
    __syncthreads();   // everyone done reading W2a/W1a/B2a/W3a
    pack_path(smem, tid, w2b, w1b, b1b, b2b);
    for (int i = tid; i < 384; i += 256) ((float*)(smem + OFF_W3))[i] = w3b[i];
    __syncthreads();

    // ---- phase b: t_j + softmax + store ----
    #pragma unroll
    for (int c = 0; c < 2; ++c) {
        __builtin_amdgcn_sched_barrier(0);
        floatx4 acc[8][2];
        GEMM_CHUNK(acc, xb + 2 * c, W1, W2, B2);
        __builtin_amdgcn_sched_barrier(0);

        float p0[2][4] = {}, p1[2][4] = {}, p2[2][4] = {};
        #pragma unroll
        for (int t = 0; t < 8; ++t) {
            int n = t * 16 + col;
            float w30 = W3[n], w31 = W3[128 + n], w32 = W3[256 + n];
            #pragma unroll
            for (int mt = 0; mt < 2; ++mt)
                #pragma unroll
                for (int r = 0; r < 4; ++r) {
                    float h = fmaxf(acc[t][mt][r], 0.f);
                    p0[mt][r] = fmaf(w30, h, p0[mt][r]);
                    p1[mt][r] = fmaf(w31, h, p1[mt][r]);
                    p2[mt][r] = fmaf(w32, h, p2[mt][r]);
                }
        }
        #pragma unroll
        for (int mt = 0; mt < 2; ++mt)
            #pragma unroll
            for (int r = 0; r < 4; ++r) {
                p0[mt][r] = redcol(p0[mt][r]);
                p1[mt][r] = redcol(p1[mt][r]);
                p2[mt][r] = redcol(p2[mt][r]);
            }
        __builtin_amdgcn_sched_barrier(0);

        if (col < 4) {
            #pragma unroll
            for (int mt = 0; mt < 2; ++mt) {
                int sl = mt * 16 + quad * 4 + col;
                float t0 = SEL4(p0[mt][0], p0[mt][1], p0[mt][2], p0[mt][3], col) + b30;
                float t1 = SEL4(p1[mt][0], p1[mt][1], p1[mt][2], p1[mt][3], col) + b31;
                float t2 = SEL4(p2[mt][0], p2[mt][1], p2[mt][2], p2[mt][3], col) + b32;
                float sa = SA[c * 128 + wave * 32 + sl];
                float y0 = sa * t0, y1 = sa * t1, y2 = sa * t2;
                float m = fmaxf(y0, fmaxf(y1, y2));
                float e0 = __expf(y0 - m), e1 = __expf(y1 - m), e2 = __expf(y2 - m);
                float rs = 1.f / (e0 + e1 + e2);
                long o = (long)(blockIdx.x * 256 + c * 128 + wave * 32 + sl) * 3;
                out[o]     = e0 * rs;
                out[o + 1] = e1 * rs;
                out[o + 2] = e2 * rs;
            }
        }
        __builtin_amdgcn_sched_barrier(0);
    }
}

extern "C" void kernel_launch(void* const* d_in, const int* in_sizes, int n_in,
                              void* d_out, int out_size, void* d_ws, size_t ws_size,
                              hipStream_t stream) {
    const float* x   = (const float*)d_in[0];
    const float* w1a = (const float*)d_in[1];
    const float* w1b = (const float*)d_in[2];
    const float* b1a = (const float*)d_in[3];
    const float* b1b = (const float*)d_in[4];
    const float* w2a = (const float*)d_in[5];
    const float* w2b = (const float*)d_in[6];
    const float* b2a = (const float*)d_in[7];
    const float* b2b = (const float*)d_in[8];
    const float* w3a = (const float*)d_in[9];
    const float* w3b = (const float*)d_in[10];
    const float* b3a = (const float*)d_in[11];
    const float* b3b = (const float*)d_in[12];
    float* out = (float*)d_out;

    krone_fused<<<NBLK, 256, 0, stream>>>(x, w1a, w1b, b1a, b1b, w2a, w2b,
                                          b2a, b2b, w3a, w3b, b3a, b3b, out);
}

// Round 8
// 111.231 us; speedup vs baseline: 1.0779x; 1.0779x over previous
//
#include <hip/hip_runtime.h>
#include <hip/hip_bf16.h>

// ---------------------------------------------------------------------------
// KroneNet fused kernel v8 for MI355X (gfx950)
// out[i][j] = softmax_j( s_a[i] * t_j[i] )
// History: v4 46.5us / v5 151us (reg cap < acc -> spill) / v6 46us in 2
// dispatches / v7 50us single dispatch, 136 regs/wave -> 2 waves/SIMD
// (occupancy steps at 64/128/256), pack writes = 3.67M conflict cycles.
// v8: chase the 128-reg step. launch_bounds(512,4) (128 unified regs/wave,
// 16 waves/CU = 50% cap); acc 64 AGPR + arch VGPR squeezed <= 64 via
// per-phase x preload + per-mt b-epilogue. 512-thread blocks halve total
// pack work; pack lane remap cuts write conflicts 16-way -> <=4-way.
// ---------------------------------------------------------------------------

#define BTOT 262144
#define NBLK (BTOT / 512)   // 512 blocks x 512 samples (8 waves x 64)

typedef __attribute__((ext_vector_type(4))) float floatx4;
typedef __attribute__((ext_vector_type(8))) short bf16x8;
typedef __attribute__((ext_vector_type(4))) int  intx4;

// LDS layout (bytes), one path resident at a time
#define OFF_W2  0          // 4 ksteps * 8 ntiles * 64 lanes * 16B = 32768
#define OFF_W1  32768      // 144 * float4 (128 + 16 pad slots)    = 2304
#define OFF_B2  35072      // 128 * float                          = 512
#define OFF_W3  35584      // 384 * float (a uses 128, b uses 384) = 1536
#define OFF_SA  37120      // 512 * float (s_a per sample)         = 2048
#define LDS_TOTAL 39168

// pack two fp32 -> one dword of two bf16 (round-half-up), 3 VALU ops
static __device__ __forceinline__ int pack2bf(float lo, float hi) {
    unsigned a = __builtin_bit_cast(unsigned, lo) + 0x8000u;
    unsigned b = __builtin_bit_cast(unsigned, hi) + 0x8000u;
    return (int)__builtin_amdgcn_perm(b, a, 0x07060302u); // {b.hi16, a.hi16}
}

// compile-time-indexed 4-way select (NO dynamic register indexing)
#define SEL4(a0, a1, a2, a3, i) \
    ((i) == 0 ? (a0) : (i) == 1 ? (a1) : (i) == 2 ? (a2) : (a3))

static __device__ __forceinline__ float redcol(float v) {
    v += __shfl_xor(v, 1); v += __shfl_xor(v, 2);
    v += __shfl_xor(v, 4); v += __shfl_xor(v, 8);
    return v;
}

// W1 slot with bank-conflict padding: one extra float4 slot every 8 entries
static __device__ __forceinline__ int w1slot(int k) { return k + (k >> 3); }

// Pack one path's W2/W1/b1/b2 into LDS (512 threads, 8 iters).
// W2 mapping (verified v5-v7): float4 group u = n*32+k4, k = 4*k4:
// dest = (s*8+t)*1024 + l*16 + (k&7)*2, s=k>>5, l=((k&31)>>3)*16+(n&15),
// t = n>>4.  B-frag: lane holds B[k=quad*8+j][n=col].
// Lane remap: n = (tid&15)|(i<<4), k4 = tid>>4 -> write banks spread by
// lane&15 -> <=4-way conflict (was 16-way with u = linear tid).
static __device__ __forceinline__ void pack_path(
        unsigned char* smem, int tid,
        const float* __restrict__ w2, const float* __restrict__ w1,
        const float* __restrict__ b1, const float* __restrict__ b2) {
    const float4* w2p = (const float4*)w2;
    #pragma unroll
    for (int i = 0; i < 8; ++i) {
        int n  = (tid & 15) | (i << 4);
        int k4 = tid >> 4;
        float4 f = w2p[n * 32 + k4];
        int k = k4 * 4;
        int s = k >> 5;
        int j0 = k & 7;               // 0 or 4
        int l = ((k & 31) >> 3) * 16 + (n & 15);
        int2 pkd;
        pkd.x = pack2bf(f.x, f.y);
        pkd.y = pack2bf(f.z, f.w);
        *(int2*)(smem + OFF_W2 + (s * 8 + (n >> 4)) * 1024 + l * 16 + j0 * 2) = pkd;
    }
    if (tid < 128) {
        ((float4*)(smem + OFF_W1))[w1slot(tid)] =
            make_float4(w1[2 * tid], w1[2 * tid + 1], b1[tid], 0.f);
        ((float*)(smem + OFF_B2))[tid] = b2[tid];
    }
}

// One chunk's GEMM: acc = W2 . relu(W1.x+b1) + b2 (acc pre-init with b2).
// acc layout: (t, mt, r) -> sample mt*16+quad*4+r, n = t*16+col.
#define GEMM_CHUNK(acc, XV, W1p, W2p, B2p)                                     \
    {                                                                          \
        _Pragma("unroll")                                                      \
        for (int t = 0; t < 8; ++t) {                                          \
            float b2n = (B2p)[t * 16 + col];                                   \
            floatx4 bi = (floatx4){b2n, b2n, b2n, b2n};                        \
            _Pragma("unroll")                                                  \
            for (int mt = 0; mt < 2; ++mt) acc[t][mt] = bi;                    \
        }                                                                      \
        _Pragma("unroll")                                                      \
        for (int s = 0; s < 4; ++s) {                                          \
            intx4 af[2];                                                       \
            const int bslot = s * 36 + quad * 9;                               \
            _Pragma("unroll")                                                  \
            for (int j2 = 0; j2 < 4; ++j2) {                                   \
                float4 c0 = (W1p)[bslot + 2 * j2];                             \
                float4 c1 = (W1p)[bslot + 2 * j2 + 1];                         \
                _Pragma("unroll")                                              \
                for (int mt = 0; mt < 2; ++mt) {                               \
                    float h0 = fmaxf(fmaf((XV)[mt].x, c0.x,                    \
                                fmaf((XV)[mt].y, c0.y, c0.z)), 0.f);           \
                    float h1 = fmaxf(fmaf((XV)[mt].x, c1.x,                    \
                                fmaf((XV)[mt].y, c1.y, c1.z)), 0.f);           \
                    af[mt][j2] = pack2bf(h0, h1);                              \
                }                                                              \
            }                                                                  \
            _Pragma("unroll")                                                  \
            for (int t = 0; t < 8; ++t) {                                      \
                bf16x8 bfr = (W2p)[(s * 8 + t) * 64 + lane];                   \
                _Pragma("unroll")                                              \
                for (int mt = 0; mt < 2; ++mt)                                 \
                    acc[t][mt] = __builtin_amdgcn_mfma_f32_16x16x32_bf16(      \
                        __builtin_bit_cast(bf16x8, af[mt]), bfr,               \
                        acc[t][mt], 0, 0, 0);                                  \
            }                                                                  \
        }                                                                      \
    }

// ---------------------------------------------------------------------------
// 512 blocks x 512 threads (8 waves). Per block (512 samples):
//   xa loads -> pack a -> phase a (s_a -> LDS)
//   xb loads -> repack b -> phase b (t_j, softmax with LDS s_a, store out)
// ---------------------------------------------------------------------------
__global__ __launch_bounds__(512, 4)
void krone_fused(const float* __restrict__ x,
                 const float* __restrict__ w1a, const float* __restrict__ w1b,
                 const float* __restrict__ b1a, const float* __restrict__ b1b,
                 const float* __restrict__ w2a, const float* __restrict__ w2b,
                 const float* __restrict__ b2a, const float* __restrict__ b2b,
                 const float* __restrict__ w3a, const float* __restrict__ w3b,
                 const float* __restrict__ b3a, const float* __restrict__ b3b,
                 float* __restrict__ out) {
    __shared__ __align__(16) unsigned char smem[LDS_TOTAL];

    const int tid  = threadIdx.x;
    const int lane = tid & 63;
    const int wave = tid >> 6;
    const int quad = lane >> 4;
    const int col  = lane & 15;
    const int wbase = blockIdx.x * 512 + wave * 64;   // this wave's 64 samples

    const bf16x8* W2 = (const bf16x8*)(smem + OFF_W2);
    const float4* W1 = (const float4*)(smem + OFF_W1);
    const float*  B2 = (const float*)(smem + OFF_B2);
    const float*  W3 = (const float*)(smem + OFF_W3);
    float*        SA = (float*)(smem + OFF_SA);
    const float2* xA = (const float2*)x;
    const float2* xB = xA + BTOT;

    const float b3a_ = b3a[0];                        // uniform -> SGPR
    const float b30 = b3b[0], b31 = b3b[1], b32 = b3b[2];

    // ---- phase a ----
    float2 xv[4];   // [c*2+mt], this phase only (8 VGPRs)
    #pragma unroll
    for (int c = 0; c < 2; ++c)
        #pragma unroll
        for (int mt = 0; mt < 2; ++mt)
            xv[c * 2 + mt] = xA[wbase + c * 32 + mt * 16 + col];

    pack_path(smem, tid, w2a, w1a, b1a, b2a);
    if (tid < 128) ((float*)(smem + OFF_W3))[tid] = w3a[tid];
    __syncthreads();

    #pragma unroll
    for (int c = 0; c < 2; ++c) {
        __builtin_amdgcn_sched_barrier(0);
        floatx4 acc[8][2];
        GEMM_CHUNK(acc, xv + 2 * c, W1, W2, B2);
        __builtin_amdgcn_sched_barrier(0);

        float pa[2][4] = {};
        #pragma unroll
        for (int t = 0; t < 8; ++t) {
            float w3n = W3[t * 16 + col];
            #pragma unroll
            for (int mt = 0; mt < 2; ++mt)
                #pragma unroll
                for (int r = 0; r < 4; ++r)
                    pa[mt][r] = fmaf(w3n, fmaxf(acc[t][mt][r], 0.f), pa[mt][r]);
        }
        #pragma unroll
        for (int mt = 0; mt < 2; ++mt)
            #pragma unroll
            for (int r = 0; r < 4; ++r) pa[mt][r] = redcol(pa[mt][r]);
        __builtin_amdgcn_sched_barrier(0);

        if (col < 4) {
            #pragma unroll
            for (int mt = 0; mt < 2; ++mt) {
                int sl = mt * 16 + quad * 4 + col;
                SA[wave * 64 + c * 32 + sl] =
                    SEL4(pa[mt][0], pa[mt][1], pa[mt][2], pa[mt][3], col) + b3a_;
            }
        }
        __builtin_amdgcn_sched_barrier(0);
    }

    // ---- phase b: reload x, repack, compute, softmax ----
    #pragma unroll
    for (int c = 0; c < 2; ++c)
        #pragma unroll
        for (int mt = 0; mt < 2; ++mt)
            xv[c * 2 + mt] = xB[wbase + c * 32 + mt * 16 + col];

    __syncthreads();   // everyone done reading W2a/W1a/B2a/W3a
    pack_path(smem, tid, w2b, w1b, b1b, b2b);
    if (tid < 384) ((float*)(smem + OFF_W3))[tid] = w3b[tid];
    __syncthreads();

    #pragma unroll
    for (int c = 0; c < 2; ++c) {
        __builtin_amdgcn_sched_barrier(0);
        floatx4 acc[8][2];
        GEMM_CHUNK(acc, xv + 2 * c, W1, W2, B2);
        __builtin_amdgcn_sched_barrier(0);

        #pragma unroll
        for (int mt = 0; mt < 2; ++mt) {     // per-mt: 12 live partials
            float p0[4] = {}, p1[4] = {}, p2[4] = {};
            #pragma unroll
            for (int t = 0; t < 8; ++t) {
                int n = t * 16 + col;
                float w30 = W3[n], w31 = W3[128 + n], w32 = W3[256 + n];
                #pragma unroll
                for (int r = 0; r < 4; ++r) {
                    float h = fmaxf(acc[t][mt][r], 0.f);
                    p0[r] = fmaf(w30, h, p0[r]);
                    p1[r] = fmaf(w31, h, p1[r]);
                    p2[r] = fmaf(w32, h, p2[r]);
                }
            }
            #pragma unroll
            for (int r = 0; r < 4; ++r) {
                p0[r] = redcol(p0[r]);
                p1[r] = redcol(p1[r]);
                p2[r] = redcol(p2[r]);
            }
            if (col < 4) {
                int sl = mt * 16 + quad * 4 + col;
                float t0 = SEL4(p0[0], p0[1], p0[2], p0[3], col) + b30;
                float t1 = SEL4(p1[0], p1[1], p1[2], p1[3], col) + b31;
                float t2 = SEL4(p2[0], p2[1], p2[2], p2[3], col) + b32;
                float sa = SA[wave * 64 + c * 32 + sl];
                float y0 = sa * t0, y1 = sa * t1, y2 = sa * t2;
                float m = fmaxf(y0, fmaxf(y1, y2));
                float e0 = __expf(y0 - m), e1 = __expf(y1 - m), e2 = __expf(y2 - m);
                float rs = 1.f / (e0 + e1 + e2);
                long o = (long)(wbase + c * 32 + sl) * 3;
                out[o]     = e0 * rs;
                out[o + 1] = e1 * rs;
                out[o + 2] = e2 * rs;
            }
        }
        __builtin_amdgcn_sched_barrier(0);
    }
}

extern "C" void kernel_launch(void* const* d_in, const int* in_sizes, int n_in,
                              void* d_out, int out_size, void* d_ws, size_t ws_size,
                              hipStream_t stream) {
    const float* x   = (const float*)d_in[0];
    const float* w1a = (const float*)d_in[1];
    const float* w1b = (const float*)d_in[2];
    const float* b1a = (const float*)d_in[3];
    const float* b1b = (const float*)d_in[4];
    const float* w2a = (const float*)d_in[5];
    const float* w2b = (const float*)d_in[6];
    const float* b2a = (const float*)d_in[7];
    const float* b2b = (const float*)d_in[8];
    const float* w3a = (const float*)d_in[9];
    const float* w3b = (const float*)d_in[10];
    const float* b3a = (const float*)d_in[11];
    const float* b3b = (const float*)d_in[12];
    float* out = (float*)d_out;

    krone_fused<<<NBLK, 512, 0, stream>>>(x, w1a, w1b, b1a, b1b, w2a, w2b,
                                          b2a, b2b, w3a, w3b, b3a, b3b, out);
}